// Round 2
// baseline (39334.204 us; speedup 1.0000x reference)
//
#include <hip/hip_runtime.h>

#define TC 32          // time steps per chunk
#define NCHUNK 16

typedef __attribute__((ext_vector_type(8))) short short8;
typedef __attribute__((ext_vector_type(4))) float float4_t;
typedef __attribute__((ext_vector_type(4))) unsigned int uint4_t;
typedef __attribute__((ext_vector_type(4))) unsigned short ushort4_t;

__device__ inline unsigned short f2bf(float f) {
  union { float f; unsigned u; } v; v.f = f;
  return (unsigned short)((v.u + 0x7fffu + ((v.u >> 16) & 1u)) >> 16);
}
__device__ inline float bf2f(unsigned short b) {
  union { unsigned u; float f; } v; v.u = ((unsigned)b) << 16;
  return v.f;
}
__device__ inline float sigmoidf_(float x) { return 1.f / (1.f + __expf(-x)); }
__device__ inline float tanhf_(float x) {
  float e = __expf(-2.f * fabsf(x));
  float t = (1.f - e) / (1.f + e);
  return x < 0.f ? -t : t;
}

// ---------------- K0: fp32 -> bf16 convert, two sources concatenated ----------------
__global__ __launch_bounds__(256)
void k_cvt2(const float* __restrict__ a, const float* __restrict__ b,
            unsigned short* __restrict__ o, unsigned halfElems) {
  const size_t i = ((size_t)blockIdx.x * 256 + threadIdx.x) * 8;
  const float* s = (i < (size_t)halfElems) ? (a + i) : (b + (i - halfElems));
  float4_t x = *(const float4_t*)s;
  float4_t y = *(const float4_t*)(s + 4);
  short8 v;
  v[0]=(short)f2bf(x.x); v[1]=(short)f2bf(x.y); v[2]=(short)f2bf(x.z); v[3]=(short)f2bf(x.w);
  v[4]=(short)f2bf(y.x); v[5]=(short)f2bf(y.y); v[6]=(short)f2bf(y.z); v[7]=(short)f2bf(y.w);
  *(short8*)(o + i) = v;
}

// ---------------- K1: embedding gather for one chunk (2 windows x 2048 rows) ----------------
__global__ __launch_bounds__(256)
void k_embed_c(const int* __restrict__ src, const float* __restrict__ emb,
               unsigned short* __restrict__ o, int rowF0, int rowB0) {
  const int wi = blockIdx.x * 4 + (threadIdx.x >> 6);  // 0..4095
  const int lane = threadIdx.x & 63;
  const int half = wi >> 11;
  const int rl = wi & 2047;
  const int row = (half ? rowB0 : rowF0) + rl;
  const int tok = src[row];
  short8 v;
  if (tok == 0) {
    v = (short8){0,0,0,0,0,0,0,0};
  } else {
    const float* ep = emb + (size_t)tok * 512 + lane * 8;
    float4_t a = *(const float4_t*)(ep);
    float4_t b = *(const float4_t*)(ep + 4);
    v[0]=(short)f2bf(a.x); v[1]=(short)f2bf(a.y); v[2]=(short)f2bf(a.z); v[3]=(short)f2bf(a.w);
    v[4]=(short)f2bf(b.x); v[5]=(short)f2bf(b.y); v[6]=(short)f2bf(b.z); v[7]=(short)f2bf(b.w);
  }
  *(short8*)(o + ((size_t)half * 2048 + rl) * 512 + lane * 8) = v;
}

// ---------------- K2: chunk x_proj GEMM: [2048,512] x [4096,512]^T per half ----------------
// xp layout per half: 16x16 tiles, tile (mt,nt) at (mt*256+nt)*256, elem order lane*4+reg
__global__ __launch_bounds__(256, 2)
void k_xproj(const unsigned short* __restrict__ Aall,   // embed_c [2][2048][512]
             const unsigned short* __restrict__ Ball,   // wih_b   [8192][512]
             const float* __restrict__ bih_f, const float* __restrict__ bhh_f,
             const float* __restrict__ bih_b, const float* __restrict__ bhh_b,
             unsigned short* __restrict__ xp) {
  __shared__ __align__(16) unsigned short lA[128 * 64];
  __shared__ __align__(16) unsigned short lB[128 * 64];
  const int tid = threadIdx.x;
  const int lane = tid & 63;
  const int w = tid >> 6;
  const int mq = w & 1, nq = w >> 1;
  const int half = blockIdx.x >> 9;      // 0 = fwd gates, 1 = bwd gates
  const int idx = blockIdx.x & 511;
  const int bm = idx & 15;               // 16 M-blocks (2048 rows)
  const int bn = idx >> 4;               // 32 N-blocks (4096 cols)
  const unsigned short* A  = Aall + (size_t)half * 1048576;
  const unsigned short* Bw = Ball + (size_t)half * 2097152;

  float4_t acc[4][4];
#pragma unroll
  for (int i = 0; i < 4; ++i)
#pragma unroll
    for (int j = 0; j < 4; ++j) acc[i][j] = (float4_t){0.f, 0.f, 0.f, 0.f};

  for (int kc = 0; kc < 8; ++kc) {
    __syncthreads();
#pragma unroll
    for (int i = 0; i < 4; ++i) {
      const int r = i * 32 + (tid >> 3);
      const int g = tid & 7;
      const int p = g ^ (r & 7);
      uint4_t va = *(const uint4_t*)(A + (size_t)(bm * 128 + r) * 512 + kc * 64 + g * 8);
      *(uint4_t*)&lA[r * 64 + p * 8] = va;
      uint4_t vb = *(const uint4_t*)(Bw + (size_t)(bn * 128 + r) * 512 + kc * 64 + g * 8);
      *(uint4_t*)&lB[r * 64 + p * 8] = vb;
    }
    __syncthreads();
#pragma unroll
    for (int ks = 0; ks < 2; ++ks) {
      short8 af[4], bf[4];
#pragma unroll
      for (int i = 0; i < 4; ++i) {
        const int m = mq * 64 + i * 16 + (lane & 15);
        const int blkm = ((lane >> 4) + 4 * ks) ^ (m & 7);
        af[i] = *(const short8*)&lA[m * 64 + blkm * 8];
        const int n = nq * 64 + i * 16 + (lane & 15);
        const int blkn = ((lane >> 4) + 4 * ks) ^ (n & 7);
        bf[i] = *(const short8*)&lB[n * 64 + blkn * 8];
      }
#pragma unroll
      for (int i = 0; i < 4; ++i)
#pragma unroll
        for (int j = 0; j < 4; ++j)
          acc[i][j] = __builtin_amdgcn_mfma_f32_16x16x32_bf16(af[i], bf[j], acc[i][j], 0, 0, 0);
    }
  }
  float biasj[4];
#pragma unroll
  for (int j = 0; j < 4; ++j) {
    const int n = bn * 128 + nq * 64 + j * 16 + (lane & 15);   // 0..4095
    biasj[j] = half ? (bih_b[n] + bhh_b[n]) : (bih_f[n] + bhh_f[n]);
  }
#pragma unroll
  for (int i = 0; i < 4; ++i) {
    const int mt = bm * 8 + mq * 4 + i;          // 0..127
#pragma unroll
    for (int j = 0; j < 4; ++j) {
      const int nt = bn * 8 + nq * 4 + j;        // 0..255
      ushort4_t o;
      o.x = f2bf(acc[i][j].x + biasj[j]);
      o.y = f2bf(acc[i][j].y + biasj[j]);
      o.z = f2bf(acc[i][j].z + biasj[j]);
      o.w = f2bf(acc[i][j].w + biasj[j]);
      *(ushort4_t*)(xp + (size_t)half * 8388608 + ((size_t)mt * 256 + nt) * 256 + lane * 4) = o;
    }
  }
}

// ---------------- group barrier: 32 WGs sharing (dir, batch-group) ----------------
__device__ inline void group_barrier(unsigned int* cnt, unsigned int* gen) {
  __threadfence();
  __syncthreads();
  if (threadIdx.x == 0) {
    unsigned g = __hip_atomic_load(gen, __ATOMIC_RELAXED, __HIP_MEMORY_SCOPE_AGENT);
    unsigned a = __hip_atomic_fetch_add(cnt, 1u, __ATOMIC_ACQ_REL, __HIP_MEMORY_SCOPE_AGENT);
    if (a == 31u) {
      __hip_atomic_store(cnt, 0u, __ATOMIC_RELAXED, __HIP_MEMORY_SCOPE_AGENT);
      __hip_atomic_store(gen, g + 1u, __ATOMIC_RELEASE, __HIP_MEMORY_SCOPE_AGENT);
    } else {
      while (__hip_atomic_load(gen, __ATOMIC_ACQUIRE, __HIP_MEMORY_SCOPE_AGENT) == g)
        __builtin_amdgcn_s_sleep(1);
    }
  }
  __syncthreads();
  __threadfence();
}

// ---------------- K3: chunked persistent bidirectional LSTM recurrence ----------------
// 256 WGs x 512 thr. gid=blockIdx%8 -> (dir,bg); cg=blockIdx/8 (32 h-col groups).
// Sync group = 32 WGs sharing gid (same XCD under round-robin dispatch — perf only).
__global__ __launch_bounds__(512, 2)
void k_lstm(const unsigned short* __restrict__ xp,      // [2][128 mt][256 nt][256]
            const unsigned short* __restrict__ whh_b,   // [2][4096][1024]
            unsigned short* __restrict__ h_buf,         // [2 dir][2 par][64][1024]
            float* __restrict__ c_state,                // [2 dir][64][1024]
            float* __restrict__ out,                    // [64][512][1024] (atomicAdd)
            unsigned int* __restrict__ bar, int s0) {
  __shared__ __align__(16) unsigned short hT[16 * 1024]; // 32 KB; rows 0..3 alias gbuf
  const int tid = threadIdx.x;
  const int lane = tid & 63;
  const int w = tid >> 6;
  const int gt = w >> 1;   // gate: i,f,g,o
  const int jh = w & 1;    // 16-col half
  const int gid = blockIdx.x & 7;
  const int dir = gid >> 2;
  const int bg = gid & 3;
  const int cg = blockIdx.x >> 3;
  const int Bg0 = bg * 16;

  // Whh B-fragments: 128 VGPRs/wave, loaded once per launch
  short8 bfr[32];
  {
    const unsigned short* wr = whh_b + (size_t)dir * 4194304 +
        (size_t)(gt * 1024 + cg * 32 + jh * 16 + (lane & 15)) * 1024 + (lane >> 4) * 8;
#pragma unroll
    for (int ks = 0; ks < 32; ++ks) bfr[ks] = *(const short8*)(wr + ks * 32);
  }

  float* gbuf = (float*)hT;              // [4 gt][16 b][32 j] fp32 (8 KB)
  const int b16 = tid >> 5, jj = tid & 31;
  const size_t cidx = (size_t)dir * 65536 + (size_t)(Bg0 + b16) * 1024 + cg * 32 + jj;
  float c = c_state[cidx];

  const int sr = tid >> 5, g0 = tid & 31, mrow = lane & 15;
  unsigned int* cnt = bar + gid * 16;
  unsigned int* gen = bar + 512 + gid * 16;

  for (int sl = 0; sl < TC; ++sl) {
    const int s = s0 + sl;
    const int t = dir ? (511 - s) : s;
    // stage h_prev [16][1024] bf16, XOR-swizzled 16B blocks
    const unsigned short* hbase = h_buf + (size_t)(dir * 2 + ((s + 1) & 1)) * 65536;
    uint4_t hv[4];
#pragma unroll
    for (int i = 0; i < 4; ++i)
      hv[i] = *(const uint4_t*)(hbase + (size_t)(Bg0 + sr) * 1024 + (size_t)(g0 + 32 * i) * 8);
    // xp accumulator-init fragment (C-layout, coalesced 8B/lane)
    const int mtl = (dir ? (TC - 1 - sl) : sl) * 4 + bg;
    const int ntl = gt * 64 + cg * 2 + jh;
    ushort4_t xpv = *(const ushort4_t*)(xp + (size_t)dir * 8388608 +
                                        ((size_t)mtl * 256 + ntl) * 256 + lane * 4);
#pragma unroll
    for (int i = 0; i < 4; ++i) {
      const int g = g0 + 32 * i;
      *(uint4_t*)&hT[sr * 1024 + ((g ^ sr) * 8)] = hv[i];
    }
    __syncthreads();
    // gates[16b x 16col] over K=1024, two interleaved acc chains
    float4_t acc0 = {bf2f(xpv.x), bf2f(xpv.y), bf2f(xpv.z), bf2f(xpv.w)};
    float4_t acc1 = {0.f, 0.f, 0.f, 0.f};
#pragma unroll
    for (int ks = 0; ks < 32; ks += 2) {
      const int blk0 = (ks * 4 + (lane >> 4)) ^ mrow;
      const int blk1 = (ks * 4 + 4 + (lane >> 4)) ^ mrow;
      short8 a0 = *(const short8*)&hT[mrow * 1024 + blk0 * 8];
      short8 a1 = *(const short8*)&hT[mrow * 1024 + blk1 * 8];
      acc0 = __builtin_amdgcn_mfma_f32_16x16x32_bf16(a0, bfr[ks], acc0, 0, 0, 0);
      acc1 = __builtin_amdgcn_mfma_f32_16x16x32_bf16(a1, bfr[ks + 1], acc1, 0, 0, 0);
    }
    __syncthreads();  // hT reads done before gbuf (aliased) writes
#pragma unroll
    for (int r = 0; r < 4; ++r) {
      float v = acc0[r] + acc1[r];
      v = (gt == 2) ? tanhf_(v) : sigmoidf_(v);
      gbuf[gt * 512 + ((lane >> 4) * 4 + r) * 32 + jh * 16 + (lane & 15)] = v;
    }
    __syncthreads();
    {
      const int base = b16 * 32 + jj;
      const float ig = gbuf[base];
      const float fg = gbuf[512 + base];
      const float gg = gbuf[1024 + base];
      const float og = gbuf[1536 + base];
      c = fg * c + ig * gg;
      const float hvv = og * tanhf_(c);
      h_buf[(size_t)(dir * 2 + (s & 1)) * 65536 + (size_t)(Bg0 + b16) * 1024 + cg * 32 + jj] = f2bf(hvv);
      atomicAdd(out + ((size_t)(Bg0 + b16) * 512 + t) * 1024 + cg * 32 + jj, hvv);
    }
    group_barrier(cnt, gen);
  }
  c_state[cidx] = c;
}

extern "C" void kernel_launch(void* const* d_in, const int* in_sizes, int n_in,
                              void* d_out, int out_size, void* d_ws, size_t ws_size,
                              hipStream_t stream) {
  const int*   src  = (const int*)d_in[0];
  const float* emb  = (const float*)d_in[1];
  const float* WihF = (const float*)d_in[2];
  const float* WhhF = (const float*)d_in[3];
  const float* bihF = (const float*)d_in[4];
  const float* bhhF = (const float*)d_in[5];
  const float* WihB = (const float*)d_in[6];
  const float* WhhB = (const float*)d_in[7];
  const float* bihB = (const float*)d_in[8];
  const float* bhhB = (const float*)d_in[9];
  float* out = (float*)d_out;
  char* ws = (char*)d_ws;

  // ws layout (total ~61 MB)
  unsigned short* wih_b   = (unsigned short*)(ws);                    //  8 MB
  unsigned short* whh_b   = (unsigned short*)(ws + 8388608ull);       // 16 MB
  unsigned short* embed_c = (unsigned short*)(ws + 25165824ull);      //  4 MB
  unsigned short* xp      = (unsigned short*)(ws + 29360128ull);      // 32 MB
  unsigned short* hbuf    = (unsigned short*)(ws + 62914560ull);      // 512 KB
  float*          cstate  = (float*)         (ws + 63438848ull);      // 512 KB
  unsigned int*   bar     = (unsigned int*)  (ws + 63963136ull);      //   8 KB

  hipMemsetAsync(hbuf, 0, 524288ull + 524288ull + 8192ull, stream);   // h, c, bar
  hipMemsetAsync(out, 0, (size_t)64 * 512 * 1024 * 4, stream);        // atomicAdd target
  k_cvt2<<<2048, 256, 0, stream>>>(WihF, WihB, wih_b, 4096u * 512u);
  k_cvt2<<<4096, 256, 0, stream>>>(WhhF, WhhB, whh_b, 4096u * 1024u);

  for (int ch = 0; ch < NCHUNK; ++ch) {
    const int tF0 = ch * TC;
    const int tB0 = 512 - TC - ch * TC;
    k_embed_c<<<1024, 256, 0, stream>>>(src, emb, embed_c, tF0 * 64, tB0 * 64);
    k_xproj<<<1024, 256, 0, stream>>>(embed_c, wih_b, bihF, bhhF, bihB, bhhB, xp);
    k_lstm<<<256, 512, 0, stream>>>(xp, whh_b, hbuf, cstate, out, bar, ch * TC);
  }
}

// Round 3
// 5950.640 us; speedup vs baseline: 6.6101x; 6.6101x over previous
//
#include <hip/hip_runtime.h>

#define TC 32          // time steps per chunk
#define NCHUNK 16

typedef __attribute__((ext_vector_type(8))) short short8;
typedef __attribute__((ext_vector_type(4))) float float4_t;
typedef __attribute__((ext_vector_type(4))) unsigned int uint4_t;
typedef __attribute__((ext_vector_type(4))) unsigned short ushort4_t;

__device__ inline unsigned short f2bf(float f) {
  union { float f; unsigned u; } v; v.f = f;
  return (unsigned short)((v.u + 0x7fffu + ((v.u >> 16) & 1u)) >> 16);
}
__device__ inline float bf2f(unsigned short b) {
  union { unsigned u; float f; } v; v.u = ((unsigned)b) << 16;
  return v.f;
}
__device__ inline float sigmoidf_(float x) { return 1.f / (1.f + __expf(-x)); }
__device__ inline float tanhf_(float x) {
  float e = __expf(-2.f * fabsf(x));
  float t = (1.f - e) / (1.f + e);
  return x < 0.f ? -t : t;
}

// ---------------- K0: fp32 -> bf16 convert, two sources concatenated ----------------
__global__ __launch_bounds__(256)
void k_cvt2(const float* __restrict__ a, const float* __restrict__ b,
            unsigned short* __restrict__ o, unsigned halfElems) {
  const size_t i = ((size_t)blockIdx.x * 256 + threadIdx.x) * 8;
  const float* s = (i < (size_t)halfElems) ? (a + i) : (b + (i - halfElems));
  float4_t x = *(const float4_t*)s;
  float4_t y = *(const float4_t*)(s + 4);
  short8 v;
  v[0]=(short)f2bf(x.x); v[1]=(short)f2bf(x.y); v[2]=(short)f2bf(x.z); v[3]=(short)f2bf(x.w);
  v[4]=(short)f2bf(y.x); v[5]=(short)f2bf(y.y); v[6]=(short)f2bf(y.z); v[7]=(short)f2bf(y.w);
  *(short8*)(o + i) = v;
}

// ---------------- K1: embedding gather for one chunk (2 windows x 2048 rows) ----------------
__global__ __launch_bounds__(256)
void k_embed_c(const int* __restrict__ src, const float* __restrict__ emb,
               unsigned short* __restrict__ o, int rowF0, int rowB0) {
  const int wi = blockIdx.x * 4 + (threadIdx.x >> 6);  // 0..4095
  const int lane = threadIdx.x & 63;
  const int half = wi >> 11;
  const int rl = wi & 2047;
  const int row = (half ? rowB0 : rowF0) + rl;
  const int tok = src[row];
  short8 v;
  if (tok == 0) {
    v = (short8){0,0,0,0,0,0,0,0};
  } else {
    const float* ep = emb + (size_t)tok * 512 + lane * 8;
    float4_t a = *(const float4_t*)(ep);
    float4_t b = *(const float4_t*)(ep + 4);
    v[0]=(short)f2bf(a.x); v[1]=(short)f2bf(a.y); v[2]=(short)f2bf(a.z); v[3]=(short)f2bf(a.w);
    v[4]=(short)f2bf(b.x); v[5]=(short)f2bf(b.y); v[6]=(short)f2bf(b.z); v[7]=(short)f2bf(b.w);
  }
  *(short8*)(o + ((size_t)half * 2048 + rl) * 512 + lane * 8) = v;
}

// ---------------- K2: chunk x_proj GEMM: [2048,512] x [4096,512]^T per half ----------------
// xp layout per half: 16x16 tiles, tile (mt,nt) at (mt*256+nt)*256, elem order lane*4+reg
__global__ __launch_bounds__(256, 2)
void k_xproj(const unsigned short* __restrict__ Aall,   // embed_c [2][2048][512]
             const unsigned short* __restrict__ Ball,   // wih_b   [8192][512]
             const float* __restrict__ bih_f, const float* __restrict__ bhh_f,
             const float* __restrict__ bih_b, const float* __restrict__ bhh_b,
             unsigned short* __restrict__ xp) {
  __shared__ __align__(16) unsigned short lA[128 * 64];
  __shared__ __align__(16) unsigned short lB[128 * 64];
  const int tid = threadIdx.x;
  const int lane = tid & 63;
  const int w = tid >> 6;
  const int mq = w & 1, nq = w >> 1;
  const int half = blockIdx.x >> 9;      // 0 = fwd gates, 1 = bwd gates
  const int idx = blockIdx.x & 511;
  const int bm = idx & 15;               // 16 M-blocks (2048 rows)
  const int bn = idx >> 4;               // 32 N-blocks (4096 cols)
  const unsigned short* A  = Aall + (size_t)half * 1048576;
  const unsigned short* Bw = Ball + (size_t)half * 2097152;

  float4_t acc[4][4];
#pragma unroll
  for (int i = 0; i < 4; ++i)
#pragma unroll
    for (int j = 0; j < 4; ++j) acc[i][j] = (float4_t){0.f, 0.f, 0.f, 0.f};

  for (int kc = 0; kc < 8; ++kc) {
    __syncthreads();
#pragma unroll
    for (int i = 0; i < 4; ++i) {
      const int r = i * 32 + (tid >> 3);
      const int g = tid & 7;
      const int p = g ^ (r & 7);
      uint4_t va = *(const uint4_t*)(A + (size_t)(bm * 128 + r) * 512 + kc * 64 + g * 8);
      *(uint4_t*)&lA[r * 64 + p * 8] = va;
      uint4_t vb = *(const uint4_t*)(Bw + (size_t)(bn * 128 + r) * 512 + kc * 64 + g * 8);
      *(uint4_t*)&lB[r * 64 + p * 8] = vb;
    }
    __syncthreads();
#pragma unroll
    for (int ks = 0; ks < 2; ++ks) {
      short8 af[4], bf[4];
#pragma unroll
      for (int i = 0; i < 4; ++i) {
        const int m = mq * 64 + i * 16 + (lane & 15);
        const int blkm = ((lane >> 4) + 4 * ks) ^ (m & 7);
        af[i] = *(const short8*)&lA[m * 64 + blkm * 8];
        const int n = nq * 64 + i * 16 + (lane & 15);
        const int blkn = ((lane >> 4) + 4 * ks) ^ (n & 7);
        bf[i] = *(const short8*)&lB[n * 64 + blkn * 8];
      }
#pragma unroll
      for (int i = 0; i < 4; ++i)
#pragma unroll
        for (int j = 0; j < 4; ++j)
          acc[i][j] = __builtin_amdgcn_mfma_f32_16x16x32_bf16(af[i], bf[j], acc[i][j], 0, 0, 0);
    }
  }
  float biasj[4];
#pragma unroll
  for (int j = 0; j < 4; ++j) {
    const int n = bn * 128 + nq * 64 + j * 16 + (lane & 15);   // 0..4095
    biasj[j] = half ? (bih_b[n] + bhh_b[n]) : (bih_f[n] + bhh_f[n]);
  }
#pragma unroll
  for (int i = 0; i < 4; ++i) {
    const int mt = bm * 8 + mq * 4 + i;          // 0..127
#pragma unroll
    for (int j = 0; j < 4; ++j) {
      const int nt = bn * 8 + nq * 4 + j;        // 0..255
      ushort4_t o;
      o.x = f2bf(acc[i][j].x + biasj[j]);
      o.y = f2bf(acc[i][j].y + biasj[j]);
      o.z = f2bf(acc[i][j].z + biasj[j]);
      o.w = f2bf(acc[i][j].w + biasj[j]);
      *(ushort4_t*)(xp + (size_t)half * 8388608 + ((size_t)mt * 256 + nt) * 256 + lane * 4) = o;
    }
  }
}

// ---------------- K3: one LSTM time-step (both dirs). Kernel boundary = grid barrier. ----
// 128 WGs x 256 thr. WG = (dir = bid>>6, cg = bid&63 -> h-cols [cg*16, cg*16+16)).
// 4 waves = 4 gates. Wave computes gates[64 b x 16 cols], K=1024 in 4 LDS chunks of 256.
__global__ __launch_bounds__(256)
void k_step(const unsigned short* __restrict__ xp,      // [2][128 mt][256 nt][256]
            const unsigned short* __restrict__ whh_b,   // [2][4096][1024]
            unsigned short* __restrict__ h_buf,         // [2 dir][2 par][64][1024] bf16
            float* __restrict__ c_state,                // [2 dir][64][1024] fp32
            float* __restrict__ out,                    // [64][512][1024] fp32
            int s) {
  __shared__ __align__(16) unsigned short hS[64 * 256]; // 32 KB A-chunk
  __shared__ float gbuf[4096];                          // 16 KB gate exchange
  const int tid = threadIdx.x;
  const int lane = tid & 63;
  const int gt = tid >> 6;            // wave = gate (i,f,g,o)
  const int dir = blockIdx.x >> 6;
  const int cg = blockIdx.x & 63;
  const int t = dir ? (511 - s) : s;

  // ---- xp accumulator init (C-fragment tiles, coalesced 8B/lane)
  const int mtlbase = (dir ? (31 - (s & 31)) : (s & 31)) * 4;
  const int ntl = gt * 64 + cg;
  float4_t acc[4];
#pragma unroll
  for (int mt = 0; mt < 4; ++mt) {
    ushort4_t xpv = *(const ushort4_t*)(xp + (size_t)dir * 8388608 +
                                        ((size_t)(mtlbase + mt) * 256 + ntl) * 256 + lane * 4);
    acc[mt] = (float4_t){bf2f(xpv.x), bf2f(xpv.y), bf2f(xpv.z), bf2f(xpv.w)};
  }

  const unsigned short* hbase = h_buf + (size_t)(dir * 2 + ((s + 1) & 1)) * 65536;
  const unsigned short* wrow = whh_b + (size_t)dir * 4194304 +
      (size_t)(gt * 1024 + cg * 16 + (lane & 15)) * 1024 + (lane >> 4) * 8;
  const int sr = tid >> 2;            // stage row (batch) 0..63
  const int sg = tid & 3;
  const int mrow = lane & 15;

  for (int kc = 0; kc < 4; ++kc) {
    // prefetch B-fragments for this K-chunk (L2-resident weights)
    short8 bf[8];
#pragma unroll
    for (int ks = 0; ks < 8; ++ks) bf[ks] = *(const short8*)(wrow + kc * 256 + ks * 32);
    // stage A chunk [64 b x 256 k], XOR-swizzled 16B blocks
    uint4_t hv[8];
#pragma unroll
    for (int i = 0; i < 8; ++i) {
      const int g = sg + 4 * i;       // 64B-contiguous per 4 threads
      hv[i] = *(const uint4_t*)(hbase + (size_t)sr * 1024 + kc * 256 + g * 8);
    }
    if (kc) __syncthreads();          // prior chunk's frag reads done
#pragma unroll
    for (int i = 0; i < 8; ++i) {
      const int g = sg + 4 * i;
      *(uint4_t*)&hS[sr * 256 + ((g ^ (sr & 31)) * 8)] = hv[i];
    }
    __syncthreads();
#pragma unroll
    for (int ks = 0; ks < 8; ++ks) {
#pragma unroll
      for (int mt = 0; mt < 4; ++mt) {
        const int m = mt * 16 + mrow;
        const int phys = (ks * 4 + (lane >> 4)) ^ (m & 31);
        short8 a = *(const short8*)&hS[m * 256 + phys * 8];
        acc[mt] = __builtin_amdgcn_mfma_f32_16x16x32_bf16(a, bf[ks], acc[mt], 0, 0, 0);
      }
    }
  }

  // ---- activations -> gbuf [4 gt][64 b][16 col]
#pragma unroll
  for (int mt = 0; mt < 4; ++mt) {
#pragma unroll
    for (int r = 0; r < 4; ++r) {
      float v = acc[mt][r];
      v = (gt == 2) ? tanhf_(v) : sigmoidf_(v);
      gbuf[gt * 1024 + (mt * 16 + (lane >> 4) * 4 + r) * 16 + (lane & 15)] = v;
    }
  }
  __syncthreads();

  // ---- elementwise: thread owns (b = tid>>2, 4 cols at (tid&3)*4)
  {
    const int b = tid >> 2;
    const int cb = (tid & 3) * 4;
    float4_t ig = *(float4_t*)&gbuf[b * 16 + cb];
    float4_t fg = *(float4_t*)&gbuf[1024 + b * 16 + cb];
    float4_t gg = *(float4_t*)&gbuf[2048 + b * 16 + cb];
    float4_t og = *(float4_t*)&gbuf[3072 + b * 16 + cb];
    float* cp = c_state + (size_t)dir * 65536 + (size_t)b * 1024 + cg * 16 + cb;
    float4_t c = *(float4_t*)cp;
    c.x = fg.x * c.x + ig.x * gg.x;
    c.y = fg.y * c.y + ig.y * gg.y;
    c.z = fg.z * c.z + ig.z * gg.z;
    c.w = fg.w * c.w + ig.w * gg.w;
    *(float4_t*)cp = c;
    float4_t hvv;
    hvv.x = og.x * tanhf_(c.x);
    hvv.y = og.y * tanhf_(c.y);
    hvv.z = og.z * tanhf_(c.z);
    hvv.w = og.w * tanhf_(c.w);
    ushort4_t hb;
    hb.x = f2bf(hvv.x); hb.y = f2bf(hvv.y); hb.z = f2bf(hvv.z); hb.w = f2bf(hvv.w);
    *(ushort4_t*)(h_buf + (size_t)(dir * 2 + (s & 1)) * 65536 +
                  (size_t)b * 1024 + cg * 16 + cb) = hb;
    // output merge: earlier-launched dir plain-stores, later one RMWs (ordered by launches)
    float* op = out + ((size_t)b * 512 + t) * 1024 + cg * 16 + cb;
    const bool first = (dir == 0) == (t < 256);
    if (first) {
      *(float4_t*)op = hvv;
    } else {
      float4_t o = *(float4_t*)op;
      o.x += hvv.x; o.y += hvv.y; o.z += hvv.z; o.w += hvv.w;
      *(float4_t*)op = o;
    }
  }
}

extern "C" void kernel_launch(void* const* d_in, const int* in_sizes, int n_in,
                              void* d_out, int out_size, void* d_ws, size_t ws_size,
                              hipStream_t stream) {
  const int*   src  = (const int*)d_in[0];
  const float* emb  = (const float*)d_in[1];
  const float* WihF = (const float*)d_in[2];
  const float* WhhF = (const float*)d_in[3];
  const float* bihF = (const float*)d_in[4];
  const float* bhhF = (const float*)d_in[5];
  const float* WihB = (const float*)d_in[6];
  const float* WhhB = (const float*)d_in[7];
  const float* bihB = (const float*)d_in[8];
  const float* bhhB = (const float*)d_in[9];
  float* out = (float*)d_out;
  char* ws = (char*)d_ws;

  // ws layout (total ~61 MB)
  unsigned short* wih_b   = (unsigned short*)(ws);                    //  8 MB
  unsigned short* whh_b   = (unsigned short*)(ws + 8388608ull);       // 16 MB
  unsigned short* embed_c = (unsigned short*)(ws + 25165824ull);      //  4 MB
  unsigned short* xp      = (unsigned short*)(ws + 29360128ull);      // 32 MB
  unsigned short* hbuf    = (unsigned short*)(ws + 62914560ull);      // 512 KB
  float*          cstate  = (float*)         (ws + 63438848ull);      // 512 KB

  hipMemsetAsync(hbuf, 0, 1048576ull, stream);                        // h ping-pong + c
  k_cvt2<<<2048, 256, 0, stream>>>(WihF, WihB, wih_b, 4096u * 512u);
  k_cvt2<<<4096, 256, 0, stream>>>(WhhF, WhhB, whh_b, 4096u * 1024u);

  for (int ch = 0; ch < NCHUNK; ++ch) {
    const int tF0 = ch * TC;
    const int tB0 = 512 - TC - ch * TC;
    k_embed_c<<<1024, 256, 0, stream>>>(src, emb, embed_c, tF0 * 64, tB0 * 64);
    k_xproj<<<1024, 256, 0, stream>>>(embed_c, wih_b, bihF, bhhF, bihB, bhhB, xp);
    for (int sl = 0; sl < TC; ++sl) {
      k_step<<<128, 256, 0, stream>>>(xp, whh_b, hbuf, cstate, out, ch * TC + sl);
    }
  }
}